// Round 3
// baseline (520.736 us; speedup 1.0000x reference)
//
#include <hip/hip_runtime.h>

// Problem constants
#define NB 8
#define NC 32
#define NL 32768
#define NK 11
#define DIL 10
#define PADS 50   // ceil(DIL*(NK-1)/2)
#define PADO 5    // (NK-1)/2
#define EPSV 1e-3f

// Tiling
#define TL    256                 // output l positions per block
#define GUARD 14                  // slack for fractional offsets
#define HALO  (PADS + GUARD)      // 64
#define SPAN  (TL + 2 * HALO)     // 384
#define OFFS  11                  // LDS stride for per-thread offsets (2-way alias = free)

__device__ __forceinline__ unsigned short f2bf(float f) {
    unsigned u = __float_as_uint(f);
    u = (u + 0x7FFFu + ((u >> 16) & 1u)) >> 16;   // RNE
    return (unsigned short)u;
}
__device__ __forceinline__ float bf2f(unsigned short h) {
    return __uint_as_float(((unsigned)h) << 16);
}

// ---------------- weight prep (all 4 transposes in one tiny kernel) ----------
// deform w [CO][CI][K] -> [K][CI][CO] ; offset w [KO][CI][KK] -> [CI][KK][KO]
#define NDW (NC * NC * NK)   // 11264
#define NOW (NK * NC * NK)   // 3872
__global__ void prep_k(const float* __restrict__ dc1_w, const float* __restrict__ dc2_w,
                       const float* __restrict__ off1_w, const float* __restrict__ off2_w,
                       float* __restrict__ wt1, float* __restrict__ wt2,
                       float* __restrict__ wto1, float* __restrict__ wto2)
{
    int i = blockIdx.x * 256 + threadIdx.x;
    if (i < NDW) {
        int co = i / (NC * NK), rem = i % (NC * NK), ci = rem / NK, k = rem % NK;
        wt1[(k * NC + ci) * NC + co] = dc1_w[i];
    } else if (i < 2 * NDW) {
        int j = i - NDW;
        int co = j / (NC * NK), rem = j % (NC * NK), ci = rem / NK, k = rem % NK;
        wt2[(k * NC + ci) * NC + co] = dc2_w[j];
    } else if (i < 2 * NDW + NOW) {
        int j = i - 2 * NDW;
        int ko = j / (NC * NK), rem = j % (NC * NK), ci = rem / NK, kk = rem % NK;
        wto1[(ci * NK + kk) * NK + ko] = off1_w[j];
    } else if (i < 2 * NDW + 2 * NOW) {
        int j = i - 2 * NDW - NOW;
        int ko = j / (NC * NK), rem = j % (NC * NK), ci = rem / NK, kk = rem % NK;
        wto2[(ci * NK + kk) * NK + ko] = off2_w[j];
    }
}

// ---------------- fused stage: [stage act tile] -> off conv -> deform -> epi --
// MODE 0: src=x, apply BN1+ReLU while staging; epilogue = BN2+ReLU -> act2
// MODE 1: src=act2 (plain stage); epilogue = +bias +resid(x) -> out
template <int MODE>
__global__ __launch_bounds__(256, 4) void fused_k(
    const float* __restrict__ src,
    const float* __restrict__ bn1g, const float* __restrict__ bn1b,
    const float* __restrict__ bn1m, const float* __restrict__ bn1v,
    const float* __restrict__ wto,     // [CI][KK][KO]
    const float* __restrict__ offbias, // [KO]
    const float* __restrict__ wt,      // [K][CI][CO]
    const float* __restrict__ dcb,     // [CO]
    const float* __restrict__ bn2g, const float* __restrict__ bn2b,
    const float* __restrict__ bn2m, const float* __restrict__ bn2v,
    const float* __restrict__ resid,   // MODE1: x
    float* __restrict__ out)
{
    __shared__ unsigned short tile[NC][SPAN];   // bf16 act tile, zeros outside [0,NL)
    __shared__ float offlds[TL * OFFS];         // per-thread offsets (runtime-k indexed)

    const int t  = threadIdx.x;
    const int b  = blockIdx.x >> 7;             // NL/TL = 128 tiles per batch
    const int l0 = (blockIdx.x & 127) * TL;
    const int s0 = l0 - HALO;
    const int l  = l0 + t;
    const float* sb = src + (long)b * NC * NL;

    // ---- stage (threads 0..191 write a packed bf16 pair per channel) ----
    {
        const int j = 2 * t;
        if (j < SPAN) {
            const int g0 = s0 + j;
            for (int c = 0; c < NC; ++c) {
                float sc = 1.f, sh = 0.f;
                if (MODE == 0) {
                    sc = bn1g[c] * rsqrtf(bn1v[c] + EPSV);
                    sh = bn1b[c] - bn1m[c] * sc;
                }
                const float* row = sb + (long)c * NL;
                float a0 = 0.f, a1 = 0.f;
                if (g0 >= 0 && g0 < NL) {
                    a0 = row[g0];
                    if (MODE == 0) a0 = fmaxf(fmaf(a0, sc, sh), 0.f);
                }
                if (g0 + 1 >= 0 && g0 + 1 < NL) {
                    a1 = row[g0 + 1];
                    if (MODE == 0) a1 = fmaxf(fmaf(a1, sc, sh), 0.f);
                }
                *reinterpret_cast<unsigned*>(&tile[c][j]) =
                    (unsigned)f2bf(a0) | ((unsigned)f2bf(a1) << 16);
            }
        }
    }
    __syncthreads();

    // ---- offset-predicting conv (reads the ±5 window from LDS) ----
    {
        float oa[NK];
        #pragma unroll
        for (int ko = 0; ko < NK; ++ko) oa[ko] = offbias[ko];
        for (int c = 0; c < NC; ++c) {
            const unsigned short* rowp = &tile[c][t + HALO - PADO];
            float v[NK];
            #pragma unroll
            for (int kk = 0; kk < NK; ++kk) v[kk] = bf2f(rowp[kk]);
            const float* wc = wto + c * NK * NK;   // uniform -> s_loads
            #pragma unroll
            for (int kk = 0; kk < NK; ++kk)
                #pragma unroll
                for (int ko = 0; ko < NK; ++ko)
                    oa[ko] = fmaf(v[kk], wc[kk * NK + ko], oa[ko]);
        }
        #pragma unroll
        for (int ko = 0; ko < NK; ++ko) offlds[t * OFFS + ko] = oa[ko];
        // no barrier needed: each thread reads back only its own slots
    }

    // ---- deformable conv ----
    float acc[NC];
    #pragma unroll
    for (int co = 0; co < NC; ++co) acc[co] = 0.f;

    #pragma unroll 1
    for (int k = 0; k < NK; ++k) {
        const float o    = offlds[t * OFFS + k];
        const float posf = (float)(l + k * DIL - PADS) + o;
        const float rel  = posf - (float)s0;      // exact (both multiples of pos ulp)
        const float lf   = floorf(rel);
        const float fr   = rel - lf;
        const int   lr   = (int)lf;
        const float* wk  = wt + k * NC * NC;

        if (__all(lr >= 0 && lr <= SPAN - 2)) {
            // fast path: bilinear from LDS (staged zeros give padding semantics)
            #pragma unroll 4
            for (int c = 0; c < NC; ++c) {
                float a0 = bf2f(tile[c][lr]);
                float a1 = bf2f(tile[c][lr + 1]);
                float s  = fmaf(a1 - a0, fr, a0);
                const float* wc = wk + c * NC;    // uniform+contig -> s_load_dwordx16
                #pragma unroll
                for (int co = 0; co < NC; ++co)
                    acc[co] = fmaf(s, wc[co], acc[co]);
            }
        } else {
            // exact global-space gather (taken only for |off| > GUARD)
            float lof = floorf(posf);
            float fr2 = posf - lof;
            int lo = (int)lof, hi = lo + 1;
            float ma = (lo >= 0 && lo < NL) ? 1.f : 0.f;
            float mb = (hi >= 0 && hi < NL) ? 1.f : 0.f;
            int ia = min(max(lo, 0), NL - 1);
            int ib = min(max(hi, 0), NL - 1);
            for (int c = 0; c < NC; ++c) {
                const float* row = sb + (long)c * NL;
                float a0 = row[ia], a1 = row[ib];
                if (MODE == 0) {
                    float sc = bn1g[c] * rsqrtf(bn1v[c] + EPSV);
                    float sh = bn1b[c] - bn1m[c] * sc;
                    a0 = fmaxf(fmaf(a0, sc, sh), 0.f);
                    a1 = fmaxf(fmaf(a1, sc, sh), 0.f);
                }
                a0 *= ma; a1 *= mb;
                float s = fmaf(a1 - a0, fr2, a0);
                const float* wc = wk + c * NC;
                #pragma unroll
                for (int co = 0; co < NC; ++co)
                    acc[co] = fmaf(s, wc[co], acc[co]);
            }
        }
    }

    // ---- epilogue ----
    const long obase = (long)b * NC * NL + l;
    if (MODE == 0) {
        #pragma unroll 4
        for (int co = 0; co < NC; ++co) {
            float sc = bn2g[co] * rsqrtf(bn2v[co] + EPSV);
            float sh = bn2b[co] - bn2m[co] * sc;
            out[obase + (long)co * NL] = fmaxf(fmaf(acc[co] + dcb[co], sc, sh), 0.f);
        }
    } else {
        #pragma unroll 4
        for (int co = 0; co < NC; ++co)
            out[obase + (long)co * NL] = acc[co] + dcb[co] + resid[obase + (long)co * NL];
    }
}

extern "C" void kernel_launch(void* const* d_in, const int* in_sizes, int n_in,
                              void* d_out, int out_size, void* d_ws, size_t ws_size,
                              hipStream_t stream)
{
    const float* x      = (const float*)d_in[0];
    const float* bn1_g  = (const float*)d_in[1];
    const float* bn1_b  = (const float*)d_in[2];
    const float* bn1_m  = (const float*)d_in[3];
    const float* bn1_v  = (const float*)d_in[4];
    const float* bn2_g  = (const float*)d_in[5];
    const float* bn2_b  = (const float*)d_in[6];
    const float* bn2_m  = (const float*)d_in[7];
    const float* bn2_v  = (const float*)d_in[8];
    const float* off1_w = (const float*)d_in[9];
    const float* off1_b = (const float*)d_in[10];
    const float* off2_w = (const float*)d_in[11];
    const float* off2_b = (const float*)d_in[12];
    const float* dc1_w  = (const float*)d_in[13];
    const float* dc1_b  = (const float*)d_in[14];
    const float* dc2_w  = (const float*)d_in[15];
    const float* dc2_b  = (const float*)d_in[16];
    float* out = (float*)d_out;

    // workspace: act2 (32 MiB) + transposed weights (~118 KiB)
    char* ws = (char*)d_ws;
    float* act2 = (float*)ws;
    float* wt1  = (float*)(ws + (size_t)NB * NC * NL * 4);
    float* wt2  = wt1 + NDW;
    float* wto1 = wt2 + NDW;
    float* wto2 = wto1 + NOW;

    prep_k<<<(2 * NDW + 2 * NOW + 255) / 256, 256, 0, stream>>>(
        dc1_w, dc2_w, off1_w, off2_w, wt1, wt2, wto1, wto2);

    const int grid = NB * (NL / TL);   // 1024 blocks, all co-resident at 4 blk/CU
    fused_k<0><<<grid, 256, 0, stream>>>(x, bn1_g, bn1_b, bn1_m, bn1_v,
                                         wto1, off1_b, wt1, dc1_b,
                                         bn2_g, bn2_b, bn2_m, bn2_v,
                                         nullptr, act2);
    fused_k<1><<<grid, 256, 0, stream>>>(act2, nullptr, nullptr, nullptr, nullptr,
                                         wto2, off2_b, wt2, dc2_b,
                                         nullptr, nullptr, nullptr, nullptr,
                                         x, out);
}

// Round 4
// 344.364 us; speedup vs baseline: 1.5122x; 1.5122x over previous
//
#include <hip/hip_runtime.h>

// Problem constants
#define NB 8
#define NC 32
#define NL 32768
#define NK 11
#define DIL 10
#define PADS 50   // ceil(DIL*(NK-1)/2)
#define PADO 5    // (NK-1)/2
#define EPSV 1e-3f

// Tiling
#define TL    256                 // output l positions per block
#define GUARD 14                  // offset slack; |off|>13 falls back to exact global path
#define HALO  (PADS + GUARD)      // 64
#define SPAN  (TL + 2 * HALO)     // 384 rows staged
#define NCP   40                  // row stride in ushorts: 80 B, 16B-aligned, bank-conflict-free

__device__ __forceinline__ unsigned short f2bf(float f) {
    unsigned u = __float_as_uint(f);
    u = (u + 0x7FFFu + ((u >> 16) & 1u)) >> 16;   // RNE
    return (unsigned short)u;
}
__device__ __forceinline__ float bflo(unsigned p) { return __uint_as_float(p << 16); }
__device__ __forceinline__ float bfhi(unsigned p) { return __uint_as_float(p & 0xffff0000u); }

// ---------------- weight prep ----------------
// deform w [CO][CI][K] -> [K][CI][CO] ; offset w [KO][CI][KK] -> [KK][CI][KO]
#define NDW (NC * NC * NK)   // 11264
#define NOW (NK * NC * NK)   // 3872
__global__ void prep_k(const float* __restrict__ dc1_w, const float* __restrict__ dc2_w,
                       const float* __restrict__ off1_w, const float* __restrict__ off2_w,
                       float* __restrict__ wt1, float* __restrict__ wt2,
                       float* __restrict__ wto1, float* __restrict__ wto2)
{
    int i = blockIdx.x * 256 + threadIdx.x;
    if (i < NDW) {
        int co = i / (NC * NK), rem = i % (NC * NK), ci = rem / NK, k = rem % NK;
        wt1[(k * NC + ci) * NC + co] = dc1_w[i];
    } else if (i < 2 * NDW) {
        int j = i - NDW;
        int co = j / (NC * NK), rem = j % (NC * NK), ci = rem / NK, k = rem % NK;
        wt2[(k * NC + ci) * NC + co] = dc2_w[j];
    } else if (i < 2 * NDW + NOW) {
        int j = i - 2 * NDW;
        int ko = j / (NC * NK), rem = j % (NC * NK), ci = rem / NK, kk = rem % NK;
        wto1[(kk * NC + ci) * NK + ko] = off1_w[j];
    } else if (i < 2 * NDW + 2 * NOW) {
        int j = i - 2 * NDW - NOW;
        int ko = j / (NC * NK), rem = j % (NC * NK), ci = rem / NK, kk = rem % NK;
        wto2[(kk * NC + ci) * NK + ko] = off2_w[j];
    }
}

// ---------------- fused: stage -> offset conv -> deform -> epilogue ----------
// MODE 0: src=x, BN1+ReLU while staging; epilogue BN2+ReLU -> act2
// MODE 1: src=act2; epilogue +bias +resid(x) -> out
template <int MODE>
__global__ __launch_bounds__(256, 4) void fused_k(
    const float* __restrict__ src,
    const float* __restrict__ bn1g, const float* __restrict__ bn1b,
    const float* __restrict__ bn1m, const float* __restrict__ bn1v,
    const float* __restrict__ wto,     // [KK][CI][KO]
    const float* __restrict__ offbias, // [KO]
    const float* __restrict__ wt,      // [K][CI][CO]
    const float* __restrict__ dcb,     // [CO]
    const float* __restrict__ bn2g, const float* __restrict__ bn2b,
    const float* __restrict__ bn2m, const float* __restrict__ bn2v,
    const float* __restrict__ resid,
    float* __restrict__ out)
{
    // [row][channel] bf16 tile; 80 B row stride => b128 row reads are conflict-free
    __shared__ unsigned short tile[SPAN * NCP];

    const int t  = threadIdx.x;
    const int b  = blockIdx.x >> 7;             // NL/TL = 128 tiles per batch
    const int l0 = (blockIdx.x & 127) * TL;
    const int s0 = l0 - HALO;
    const int l  = l0 + t;
    const float* sb = src + (long)b * NC * NL;

    // ---- stage: thread t fills rows t, t+256 (channels packed 8/chunk) ----
    for (int r = t; r < SPAN; r += 256) {
        const int g = s0 + r;
        const bool ok = (g >= 0 && g < NL);
        #pragma unroll
        for (int j = 0; j < 4; ++j) {
            unsigned tmp[4];
            #pragma unroll
            for (int e = 0; e < 4; ++e) {
                const int c0 = j * 8 + 2 * e;
                float v0 = 0.f, v1 = 0.f;
                if (ok) {
                    v0 = sb[(long)c0 * NL + g];
                    v1 = sb[(long)(c0 + 1) * NL + g];
                    if (MODE == 0) {
                        float sc0 = bn1g[c0] * rsqrtf(bn1v[c0] + EPSV);
                        float sh0 = bn1b[c0] - bn1m[c0] * sc0;
                        float sc1 = bn1g[c0 + 1] * rsqrtf(bn1v[c0 + 1] + EPSV);
                        float sh1 = bn1b[c0 + 1] - bn1m[c0 + 1] * sc1;
                        v0 = fmaxf(fmaf(v0, sc0, sh0), 0.f);
                        v1 = fmaxf(fmaf(v1, sc1, sh1), 0.f);
                    }
                }
                tmp[e] = (unsigned)f2bf(v0) | ((unsigned)f2bf(v1) << 16);
            }
            uint4 pk; pk.x = tmp[0]; pk.y = tmp[1]; pk.z = tmp[2]; pk.w = tmp[3];
            *reinterpret_cast<uint4*>(&tile[r * NCP + j * 8]) = pk;
        }
    }
    __syncthreads();

    // ---- offset conv: 11 taps x 32 ch, wide row reads ----
    float oa[NK];
    #pragma unroll
    for (int ko = 0; ko < NK; ++ko) oa[ko] = offbias[ko];

    #pragma unroll 1
    for (int kk = 0; kk < NK; ++kk) {
        const int rr = t + (HALO - PADO) + kk;
        const uint4* rp = reinterpret_cast<const uint4*>(&tile[rr * NCP]);
        const float* wkk = wto + kk * NC * NK;
        #pragma unroll
        for (int j = 0; j < 4; ++j) {
            const uint4 A = rp[j];
            const unsigned pw[4] = {A.x, A.y, A.z, A.w};
            #pragma unroll
            for (int e = 0; e < 4; ++e) {
                const int c0 = j * 8 + 2 * e;
                const float v0 = bflo(pw[e]);
                const float v1 = bfhi(pw[e]);
                const float* w0 = wkk + c0 * NK;       // uniform -> s_loads
                #pragma unroll
                for (int ko = 0; ko < NK; ++ko) oa[ko] = fmaf(v0, w0[ko], oa[ko]);
                #pragma unroll
                for (int ko = 0; ko < NK; ++ko) oa[ko] = fmaf(v1, w0[NK + ko], oa[ko]);
            }
        }
    }

    // ---- deformable conv (offsets stay in registers; select by uniform k) ----
    float acc[NC];
    #pragma unroll
    for (int co = 0; co < NC; ++co) acc[co] = 0.f;

    #pragma unroll 1
    for (int k = 0; k < NK; ++k) {
        float o = oa[0];
        #pragma unroll
        for (int q = 1; q < NK; ++q) if (k == q) o = oa[q];

        const float posf = (float)(l + k * DIL - PADS) + o;
        const float rel  = posf - (float)s0;     // exact in f32
        const float lf   = floorf(rel);
        const float fr   = rel - lf;
        const int   lr   = (int)lf;
        const float* wk  = wt + k * NC * NC;

        if (__all(lr >= 0 && lr <= SPAN - 2)) {
            const uint4* r0 = reinterpret_cast<const uint4*>(&tile[lr * NCP]);
            const uint4* r1 = reinterpret_cast<const uint4*>(&tile[(lr + 1) * NCP]);
            #pragma unroll
            for (int j = 0; j < 4; ++j) {
                const uint4 A0 = r0[j];
                const uint4 A1 = r1[j];
                const unsigned p0[4] = {A0.x, A0.y, A0.z, A0.w};
                const unsigned p1[4] = {A1.x, A1.y, A1.z, A1.w};
                #pragma unroll
                for (int e = 0; e < 4; ++e) {
                    const int c0 = j * 8 + 2 * e;
                    const float a0 = bflo(p0[e]), b0 = bflo(p1[e]);
                    const float a1 = bfhi(p0[e]), b1 = bfhi(p1[e]);
                    const float sA = fmaf(b0 - a0, fr, a0);
                    const float sB = fmaf(b1 - a1, fr, a1);
                    const float* wA = wk + c0 * NC;     // uniform+contig -> s_load_dwordx16
                    #pragma unroll
                    for (int co = 0; co < NC; ++co) acc[co] = fmaf(sA, wA[co], acc[co]);
                    #pragma unroll
                    for (int co = 0; co < NC; ++co) acc[co] = fmaf(sB, wA[NC + co], acc[co]);
                }
            }
        } else {
            // exact global-space fallback (|off| > GUARD-1; practically never)
            float lof = floorf(posf);
            float fr2 = posf - lof;
            int lo = (int)lof, hi = lo + 1;
            float ma = (lo >= 0 && lo < NL) ? 1.f : 0.f;
            float mb = (hi >= 0 && hi < NL) ? 1.f : 0.f;
            int ia = min(max(lo, 0), NL - 1);
            int ib = min(max(hi, 0), NL - 1);
            for (int c = 0; c < NC; ++c) {
                const float* row = sb + (long)c * NL;
                float a0 = row[ia], a1 = row[ib];
                if (MODE == 0) {
                    float sc = bn1g[c] * rsqrtf(bn1v[c] + EPSV);
                    float sh = bn1b[c] - bn1m[c] * sc;
                    a0 = fmaxf(fmaf(a0, sc, sh), 0.f);
                    a1 = fmaxf(fmaf(a1, sc, sh), 0.f);
                }
                a0 *= ma; a1 *= mb;
                float s = fmaf(a1 - a0, fr2, a0);
                const float* wc = wk + c * NC;
                #pragma unroll
                for (int co = 0; co < NC; ++co)
                    acc[co] = fmaf(s, wc[co], acc[co]);
            }
        }
    }

    // ---- epilogue ----
    const long obase = (long)b * NC * NL + l;
    if (MODE == 0) {
        #pragma unroll 4
        for (int co = 0; co < NC; ++co) {
            float sc = bn2g[co] * rsqrtf(bn2v[co] + EPSV);
            float sh = bn2b[co] - bn2m[co] * sc;
            out[obase + (long)co * NL] = fmaxf(fmaf(acc[co] + dcb[co], sc, sh), 0.f);
        }
    } else {
        #pragma unroll 4
        for (int co = 0; co < NC; ++co)
            out[obase + (long)co * NL] = acc[co] + dcb[co] + resid[obase + (long)co * NL];
    }
}

extern "C" void kernel_launch(void* const* d_in, const int* in_sizes, int n_in,
                              void* d_out, int out_size, void* d_ws, size_t ws_size,
                              hipStream_t stream)
{
    const float* x      = (const float*)d_in[0];
    const float* bn1_g  = (const float*)d_in[1];
    const float* bn1_b  = (const float*)d_in[2];
    const float* bn1_m  = (const float*)d_in[3];
    const float* bn1_v  = (const float*)d_in[4];
    const float* bn2_g  = (const float*)d_in[5];
    const float* bn2_b  = (const float*)d_in[6];
    const float* bn2_m  = (const float*)d_in[7];
    const float* bn2_v  = (const float*)d_in[8];
    const float* off1_w = (const float*)d_in[9];
    const float* off1_b = (const float*)d_in[10];
    const float* off2_w = (const float*)d_in[11];
    const float* off2_b = (const float*)d_in[12];
    const float* dc1_w  = (const float*)d_in[13];
    const float* dc1_b  = (const float*)d_in[14];
    const float* dc2_w  = (const float*)d_in[15];
    const float* dc2_b  = (const float*)d_in[16];
    float* out = (float*)d_out;

    char* ws = (char*)d_ws;
    float* act2 = (float*)ws;
    float* wt1  = (float*)(ws + (size_t)NB * NC * NL * 4);
    float* wt2  = wt1 + NDW;
    float* wto1 = wt2 + NDW;
    float* wto2 = wto1 + NOW;

    prep_k<<<(2 * NDW + 2 * NOW + 255) / 256, 256, 0, stream>>>(
        dc1_w, dc2_w, off1_w, off2_w, wt1, wt2, wto1, wto2);

    const int grid = NB * (NL / TL);   // 1024 blocks = 4/CU
    fused_k<0><<<grid, 256, 0, stream>>>(x, bn1_g, bn1_b, bn1_m, bn1_v,
                                         wto1, off1_b, wt1, dc1_b,
                                         bn2_g, bn2_b, bn2_m, bn2_v,
                                         nullptr, act2);
    fused_k<1><<<grid, 256, 0, stream>>>(act2, nullptr, nullptr, nullptr, nullptr,
                                         wto2, off2_b, wt2, dc2_b,
                                         nullptr, nullptr, nullptr, nullptr,
                                         x, out);
}

// Round 5
// 206.711 us; speedup vs baseline: 2.5192x; 1.6659x over previous
//
#include <hip/hip_runtime.h>
#include <hip/hip_bf16.h>

// Problem constants
#define NB 8
#define NC 32
#define NL 32768
#define NK 11
#define DIL 10
#define PADS 50   // ceil(DIL*(NK-1)/2)
#define PADO 5    // (NK-1)/2
#define EPSV 1e-3f

// Tiling
#define TL    256                 // output l positions per block
#define GUARD 14                  // offset slack; beyond -> exact global fallback
#define HALO  (PADS + GUARD)      // 64
#define SPAN  (TL + 2 * HALO)     // 384 rows staged
#define NCP   40                  // tile row stride in ushorts: 80 B, 16B-aligned, conflict-free

// MFMA fragment types (gfx950)
typedef __attribute__((ext_vector_type(8))) short bf16x8;
typedef __attribute__((ext_vector_type(4))) float f32x4;

// MFMA weight-fragment array sizes (ushort elements)
#define WMF_SZ  (NK * 2 * 64 * 8)   // deform: [k][half][lane][8] = 11264
#define WOMF_SZ (NK * 64 * 8)       // offset: [kk][lane][8]      = 5632

__device__ __forceinline__ unsigned short f2bf(float f) {
    unsigned u = __float_as_uint(f);
    u = (u + 0x7FFFu + ((u >> 16) & 1u)) >> 16;   // RNE
    return (unsigned short)u;
}
__device__ __forceinline__ float bflo(unsigned p) { return __uint_as_float(p << 16); }
__device__ __forceinline__ float bfhi(unsigned p) { return __uint_as_float(p & 0xffff0000u); }

// ---------------- weight prep: pack W into per-lane MFMA A-fragments ----------
// deform  A[m=co_local=lane&15][k_local=c=8*(lane>>4)+e] for co-half h, tap k
// offset  A[m=ko      =lane&15][k_local=c=8*(lane>>4)+e] for tap kk (ko>=11 -> 0)
__global__ void prep_k(const float* __restrict__ dc1_w, const float* __restrict__ dc2_w,
                       const float* __restrict__ off1_w, const float* __restrict__ off2_w,
                       unsigned short* __restrict__ wmf1, unsigned short* __restrict__ wmf2,
                       unsigned short* __restrict__ womf1, unsigned short* __restrict__ womf2)
{
    int i = blockIdx.x * 256 + threadIdx.x;
    if (i < 2 * WMF_SZ) {
        const float* w = (i < WMF_SZ) ? dc1_w : dc2_w;
        unsigned short* dst = (i < WMF_SZ) ? wmf1 : wmf2;
        int j = (i < WMF_SZ) ? i : i - WMF_SZ;
        int e = j & 7, lane = (j >> 3) & 63, k2 = j >> 9;   // k2 = k*2+h
        int k = k2 >> 1, h = k2 & 1;
        int co = h * 16 + (lane & 15);
        int c  = 8 * (lane >> 4) + e;
        dst[j] = f2bf(w[(co * NC + c) * NK + k]);           // [CO][CI][K]
    } else if (i < 2 * WMF_SZ + 2 * WOMF_SZ) {
        int i2 = i - 2 * WMF_SZ;
        const float* w = (i2 < WOMF_SZ) ? off1_w : off2_w;
        unsigned short* dst = (i2 < WOMF_SZ) ? womf1 : womf2;
        int j = (i2 < WOMF_SZ) ? i2 : i2 - WOMF_SZ;
        int e = j & 7, lane = (j >> 3) & 63, kk = j >> 9;
        int ko = lane & 15;
        int c  = 8 * (lane >> 4) + e;
        dst[j] = (ko < NK) ? f2bf(w[(ko * NC + c) * NK + kk]) : (unsigned short)0;
    }
}

// ---------------- fused: stage -> offconv(MFMA) -> deform(MFMA) -> epilogue ---
// MODE 0: src=x, BN1+ReLU while staging; epilogue BN2+ReLU -> act2
// MODE 1: src=act2; epilogue +bias +resid(x) -> out
template <int MODE>
__global__ __launch_bounds__(256, 4) void fused_k(
    const float* __restrict__ src,
    const float* __restrict__ bn1g, const float* __restrict__ bn1b,
    const float* __restrict__ bn1m, const float* __restrict__ bn1v,
    const unsigned short* __restrict__ womf,  // offset-conv A-frags
    const float* __restrict__ offb,           // [KO]
    const unsigned short* __restrict__ wmf,   // deform A-frags
    const float* __restrict__ dcb,            // [CO]
    const float* __restrict__ bn2g, const float* __restrict__ bn2b,
    const float* __restrict__ bn2m, const float* __restrict__ bn2v,
    const float* __restrict__ resid,
    float* __restrict__ out)
{
    __shared__ unsigned short tile[SPAN * NCP];   // 30720 B, [row][chan] bf16
    __shared__ float off_lds[TL * 12];            // 12288 B, [l][ko], stride 12

    const int t  = threadIdx.x;
    const int b  = blockIdx.x >> 7;               // NL/TL = 128 tiles per batch
    const int l0 = (blockIdx.x & 127) * TL;
    const int s0 = l0 - HALO;
    const float* sb = src + (long)b * NC * NL;

    // ---- stage: thread t fills rows t, t+256 ----
    for (int r = t; r < SPAN; r += 256) {
        const int g = s0 + r;
        const bool ok = (g >= 0 && g < NL);
        #pragma unroll
        for (int j = 0; j < 4; ++j) {
            unsigned tmp[4];
            #pragma unroll
            for (int e = 0; e < 4; ++e) {
                const int c0 = j * 8 + 2 * e;
                float v0 = 0.f, v1 = 0.f;
                if (ok) {
                    v0 = sb[(long)c0 * NL + g];
                    v1 = sb[(long)(c0 + 1) * NL + g];
                    if (MODE == 0) {
                        float sc0 = bn1g[c0] * rsqrtf(bn1v[c0] + EPSV);
                        float sh0 = bn1b[c0] - bn1m[c0] * sc0;
                        float sc1 = bn1g[c0 + 1] * rsqrtf(bn1v[c0 + 1] + EPSV);
                        float sh1 = bn1b[c0 + 1] - bn1m[c0 + 1] * sc1;
                        v0 = fmaxf(fmaf(v0, sc0, sh0), 0.f);
                        v1 = fmaxf(fmaf(v1, sc1, sh1), 0.f);
                    }
                }
                tmp[e] = (unsigned)f2bf(v0) | ((unsigned)f2bf(v1) << 16);
            }
            uint4 pk; pk.x = tmp[0]; pk.y = tmp[1]; pk.z = tmp[2]; pk.w = tmp[3];
            *reinterpret_cast<uint4*>(&tile[r * NCP + j * 8]) = pk;
        }
    }
    __syncthreads();

    const int lane = t & 63;
    const int w    = t >> 6;          // wave id: owns l-range [64w, 64w+64)
    const int n    = lane & 15;       // MFMA 16-dim index (l column / co row)
    const int q    = lane >> 4;       // lane quarter -> k_local = 8q+i

    // ---- offset conv via MFMA: C[ko][l] = sum_{c,kk} Wo[ko][c,kk] * act[c][l+kk-5]
    float biasq[4];
    #pragma unroll
    for (int j = 0; j < 4; ++j) {
        int ko = 4 * q + j;
        biasq[j] = (ko < NK) ? offb[ko] : 0.f;
    }

    #pragma unroll 1
    for (int lt = 0; lt < 4; ++lt) {
        const int lt0 = w * 64 + lt * 16;
        f32x4 oc = {0.f, 0.f, 0.f, 0.f};
        #pragma unroll 2
        for (int kk = 0; kk < NK; ++kk) {
            const int r = lt0 + n + (HALO - PADO) + kk;   // in [59, 324]
            bf16x8 bfrag = *reinterpret_cast<const bf16x8*>(&tile[r * NCP + 8 * q]);
            bf16x8 afrag = *reinterpret_cast<const bf16x8*>(&womf[(kk * 64 + lane) * 8]);
            oc = __builtin_amdgcn_mfma_f32_16x16x32_bf16(afrag, bfrag, oc, 0, 0, 0);
        }
        // C layout: col = lane&15 = l, row = 4q+reg = ko. q=3 rows (12..15) unused.
        if (q < 3) {
            f32x4 ov;
            #pragma unroll
            for (int j = 0; j < 4; ++j) ov[j] = oc[j] + biasq[j];
            *reinterpret_cast<f32x4*>(&off_lds[(lt0 + n) * 12 + 4 * q]) = ov;
        }
    }
    // no barrier: each wave reads back only its own l-range (same-wave LDS RAW)

    // ---- per-lane epilogue constants (co = 4q+j and 16+4q+j) ----
    float dA[4], dB[4], sA[4], hA[4], sB[4], hB[4];
    #pragma unroll
    for (int j = 0; j < 4; ++j) {
        const int c0 = 4 * q + j, c1 = c0 + 16;
        dA[j] = dcb[c0]; dB[j] = dcb[c1];
        if (MODE == 0) {
            sA[j] = bn2g[c0] * rsqrtf(bn2v[c0] + EPSV);
            hA[j] = bn2b[c0] - bn2m[c0] * sA[j];
            sB[j] = bn2g[c1] * rsqrtf(bn2v[c1] + EPSV);
            hB[j] = bn2b[c1] - bn2m[c1] * sB[j];
        }
    }

    // ---- deform via MFMA: C[co][l] = sum_k sum_c Wk[co][c] * S_k[c][l] ----
    #pragma unroll 1
    for (int lt = 0; lt < 4; ++lt) {
        const int lt0 = w * 64 + lt * 16;
        const int l   = l0 + lt0 + n;
        f32x4 acc0 = {0.f, 0.f, 0.f, 0.f};   // co-half 0
        f32x4 acc1 = {0.f, 0.f, 0.f, 0.f};   // co-half 1
        #pragma unroll 1
        for (int k = 0; k < NK; ++k) {
            const float o    = off_lds[(lt0 + n) * 12 + k];
            const float posf = (float)(l + k * DIL - PADS) + o;   // matches ref f32 math
            const float rel  = posf - (float)s0;                  // exact in f32
            const float lf   = floorf(rel);
            const float fr   = rel - lf;
            const int   lr   = (int)lf;
            float sv[8];
            if (lr >= 0 && lr <= SPAN - 2) {
                const uint4 p0 = *reinterpret_cast<const uint4*>(&tile[lr * NCP + 8 * q]);
                const uint4 p1 = *reinterpret_cast<const uint4*>(&tile[(lr + 1) * NCP + 8 * q]);
                const unsigned pa[4] = {p0.x, p0.y, p0.z, p0.w};
                const unsigned pb[4] = {p1.x, p1.y, p1.z, p1.w};
                #pragma unroll
                for (int e = 0; e < 4; ++e) {
                    const float lo0 = bflo(pa[e]), lo1 = bflo(pb[e]);
                    const float hi0 = bfhi(pa[e]), hi1 = bfhi(pb[e]);
                    sv[2 * e]     = fmaf(lo1 - lo0, fr, lo0);
                    sv[2 * e + 1] = fmaf(hi1 - hi0, fr, hi0);
                }
            } else {
                // exact global-space fallback (|off| > GUARD-1; practically never)
                const float lof = floorf(posf);
                const float fr2 = posf - lof;
                const int lo = (int)lof, hi = lo + 1;
                const float ma = (lo >= 0 && lo < NL) ? 1.f : 0.f;
                const float mb = (hi >= 0 && hi < NL) ? 1.f : 0.f;
                const int ia = min(max(lo, 0), NL - 1);
                const int ib = min(max(hi, 0), NL - 1);
                #pragma unroll
                for (int e = 0; e < 8; ++e) {
                    const int c = 8 * q + e;
                    const float* row = sb + (long)c * NL;
                    float a0 = row[ia], a1 = row[ib];
                    if (MODE == 0) {
                        float sc = bn1g[c] * rsqrtf(bn1v[c] + EPSV);
                        float sh = bn1b[c] - bn1m[c] * sc;
                        a0 = fmaxf(fmaf(a0, sc, sh), 0.f);
                        a1 = fmaxf(fmaf(a1, sc, sh), 0.f);
                    }
                    a0 *= ma; a1 *= mb;
                    sv[e] = fmaf(a1 - a0, fr2, a0);
                }
            }
            // pack S values -> bf16 B-fragment (k_local = c = 8q+e)
            union { __hip_bfloat162 h2[4]; bf16x8 v; } pk;
            #pragma unroll
            for (int e = 0; e < 4; ++e)
                pk.h2[e] = __float22bfloat162_rn(make_float2(sv[2 * e], sv[2 * e + 1]));
            const bf16x8 a0f = *reinterpret_cast<const bf16x8*>(&wmf[((k * 2 + 0) * 64 + lane) * 8]);
            const bf16x8 a1f = *reinterpret_cast<const bf16x8*>(&wmf[((k * 2 + 1) * 64 + lane) * 8]);
            acc0 = __builtin_amdgcn_mfma_f32_16x16x32_bf16(a0f, pk.v, acc0, 0, 0, 0);
            acc1 = __builtin_amdgcn_mfma_f32_16x16x32_bf16(a1f, pk.v, acc1, 0, 0, 0);
        }
        // ---- epilogue: C col = lane&15 = l, row = 4q+reg (+16 for half 1) ----
        const long ob = (long)b * NC * NL + l;
        if (MODE == 0) {
            #pragma unroll
            for (int j = 0; j < 4; ++j) {
                const int c0 = 4 * q + j, c1 = c0 + 16;
                out[ob + (long)c0 * NL] = fmaxf(fmaf(acc0[j] + dA[j], sA[j], hA[j]), 0.f);
                out[ob + (long)c1 * NL] = fmaxf(fmaf(acc1[j] + dB[j], sB[j], hB[j]), 0.f);
            }
        } else {
            #pragma unroll
            for (int j = 0; j < 4; ++j) {
                const int c0 = 4 * q + j, c1 = c0 + 16;
                out[ob + (long)c0 * NL] = acc0[j] + dA[j] + resid[ob + (long)c0 * NL];
                out[ob + (long)c1 * NL] = acc1[j] + dB[j] + resid[ob + (long)c1 * NL];
            }
        }
    }
}

extern "C" void kernel_launch(void* const* d_in, const int* in_sizes, int n_in,
                              void* d_out, int out_size, void* d_ws, size_t ws_size,
                              hipStream_t stream)
{
    const float* x      = (const float*)d_in[0];
    const float* bn1_g  = (const float*)d_in[1];
    const float* bn1_b  = (const float*)d_in[2];
    const float* bn1_m  = (const float*)d_in[3];
    const float* bn1_v  = (const float*)d_in[4];
    const float* bn2_g  = (const float*)d_in[5];
    const float* bn2_b  = (const float*)d_in[6];
    const float* bn2_m  = (const float*)d_in[7];
    const float* bn2_v  = (const float*)d_in[8];
    const float* off1_w = (const float*)d_in[9];
    const float* off1_b = (const float*)d_in[10];
    const float* off2_w = (const float*)d_in[11];
    const float* off2_b = (const float*)d_in[12];
    const float* dc1_w  = (const float*)d_in[13];
    const float* dc1_b  = (const float*)d_in[14];
    const float* dc2_w  = (const float*)d_in[15];
    const float* dc2_b  = (const float*)d_in[16];
    float* out = (float*)d_out;

    // workspace: act2 (32 MiB) + MFMA weight fragments (~67 KiB)
    char* ws = (char*)d_ws;
    float* act2 = (float*)ws;
    unsigned short* wmf1  = (unsigned short*)(ws + (size_t)NB * NC * NL * 4);
    unsigned short* wmf2  = wmf1 + WMF_SZ;
    unsigned short* womf1 = wmf2 + WMF_SZ;
    unsigned short* womf2 = womf1 + WOMF_SZ;

    prep_k<<<(2 * WMF_SZ + 2 * WOMF_SZ + 255) / 256, 256, 0, stream>>>(
        dc1_w, dc2_w, off1_w, off2_w, wmf1, wmf2, womf1, womf2);

    const int grid = NB * (NL / TL);   // 1024 blocks, 3/CU (LDS 43 KB)
    fused_k<0><<<grid, 256, 0, stream>>>(x, bn1_g, bn1_b, bn1_m, bn1_v,
                                         womf1, off1_b, wmf1, dc1_b,
                                         bn2_g, bn2_b, bn2_m, bn2_v,
                                         nullptr, act2);
    fused_k<1><<<grid, 256, 0, stream>>>(act2, nullptr, nullptr, nullptr, nullptr,
                                         womf2, off2_b, wmf2, dc2_b,
                                         nullptr, nullptr, nullptr, nullptr,
                                         x, out);
}